// Round 9
// baseline (105.220 us; speedup 1.0000x reference)
//
#include <hip/hip_runtime.h>
#include <hip/hip_bf16.h>

// Problem constants
#define NB    65536      // batch rows
#define ND    1024       // feature dim (K)
#define NT    64         // trees (N)
#define TPB   512        // threads per block (8 waves)
#define BROWS 128        // rows per block
#define SROWS 16         // rows per stripe (phase)
#define NSTR  (BROWS / SROWS)   // 8 stripes
#define NBLK  (NB / BROWS)      // 512 blocks = 2/CU exactly

typedef __attribute__((ext_vector_type(8))) short bf16x8;
typedef __attribute__((ext_vector_type(4))) short bf16x4;
typedef __attribute__((ext_vector_type(4))) float f32x4;

__device__ __forceinline__ short f2bf_s(float f) {
    __hip_bfloat16 h = __float2bfloat16(f);
    return __builtin_bit_cast(short, h);
}

// lgkm-only barrier (no vmcnt drain): LDS handoff is ordered, in-flight
// global->register loads float across (proven correct in R6).
__device__ __forceinline__ void phase_barrier() {
    asm volatile("s_waitcnt lgkmcnt(0)\n\ts_barrier" ::: "memory");
}

// ---- prep: feature_selectors [64][1024] f32 -> bf16 in d_ws (L2-resident B) ----
__global__ __launch_bounds__(256) void prep_kernel(const float* __restrict__ F,
                                                   __hip_bfloat16* __restrict__ Fb) {
    int idx = blockIdx.x * 256 + threadIdx.x;  // 256 blocks -> 65536 elements
    Fb[idx] = __float2bfloat16(F[idx]);
}

// ---- main: block owns 128 rows; phase = 16-row stripe of FULL K.
// Global reads per phase: one contiguous 64KB window (linear across phases).
// 8 waves: wave (tt = w&3, kh = w>>2) computes tree-tile tt over K-half kh.
// Per-phase epilogue: K-half sum (LDS) -> sigmoid -> tree butterfly -> store.
template <bool PREPPED>
__global__ __launch_bounds__(TPB, 4) void node_main(const float* __restrict__ x,
                                                    const void* __restrict__ Fv,
                                                    const float* __restrict__ thr,
                                                    const float* __restrict__ lw,
                                                    float* __restrict__ out) {
    __shared__ __align__(16) __hip_bfloat16 Abuf[2][SROWS * ND];  // 2 x 32 KB
    __shared__ __align__(16) float eps[4][64][4];                 // 4 KB K-half partials
    __shared__ float part[4][SROWS][2];                           // 512 B tree-tile partials

    const int tid  = threadIdx.x;
    const int wv   = tid >> 6;
    const int lane = tid & 63;
    const int c    = lane & 15;     // MFMA 16-index: batch row (A) / tree col (B)
    const int g    = lane >> 4;     // k-group
    const int tt   = wv & 3;        // tree tile (16 trees)
    const int kh   = wv >> 2;       // K half
    const long blockRow = (long)blockIdx.x * BROWS;

    // staging: thread (sr = tid>>5, q = tid&31); per instruction j: 2 rows x 512B contiguous
    const int sr = tid >> 5;        // 0..15 (stripe-local row)
    const int q  = tid & 31;        // 16B granule within 512B sub-segment
    const float* xstage = x + (blockRow + sr) * ND;

    // per-lane tree constants (tree = tt*16 + c, fixed per lane)
    const int   t     = tt * 16 + c;
    const float thr_t = thr[t];
    const float w00 = lw[t * 4 + 0], w01 = lw[t * 4 + 1];
    const float w10 = lw[t * 4 + 2], w11 = lw[t * 4 + 3];
    const float dd0 = w00 - w10, dd1 = w01 - w11;

    const __hip_bfloat16* Bb = (const __hip_bfloat16*)Fv + (long)t * ND + kh * 512;
    const float*          Bf = (const float*)Fv          + (long)t * ND + kh * 512;

    f32x4 rA0[8], rA1[8];   // stripe staging registers (stripe s -> rA[s&1])

    auto load_stripe = [&](int s, f32x4* rA) {
#pragma unroll
        for (int j = 0; j < 8; ++j)
            rA[j] = *(const f32x4*)(xstage + (long)s * SROWS * ND + (q + 32 * j) * 4);
    };
    auto stage_write = [&](int buf, const f32x4* rA) {
#pragma unroll
        for (int j = 0; j < 8; ++j) {
            f32x4 a = rA[j];
            bf16x4 v;
            v[0] = f2bf_s(a[0]); v[1] = f2bf_s(a[1]);
            v[2] = f2bf_s(a[2]); v[3] = f2bf_s(a[3]);
            const int gran = q + 32 * j;                 // 8B granule, 0..255
            const int slot = (gran >> 1) ^ (sr & 7);     // 16B slot, XOR swizzle
            char* p = (char*)(&Abuf[buf][0]) + sr * 2048 + (slot << 4) + ((gran & 1) << 3);
            *(bf16x4*)p = v;
        }
    };

    // prologue: stripe 0 staged, stripe 1 in flight
    load_stripe(0, rA0);
    stage_write(0, rA0);
    load_stripe(1, rA1);
    phase_barrier();

#pragma unroll
    for (int s = 0; s < NSTR; ++s) {
        // issue stripe s+2 loads early; stage stripe s+1 (its rA landed a phase ago)
        if (s + 2 < NSTR) load_stripe(s + 2, (s & 1) ? rA1 : rA0);
        if (s + 1 < NSTR) stage_write((s + 1) & 1, ((s + 1) & 1) ? rA1 : rA0);

        // ---- compute stripe s: 16 MFMAs over this wave's K-half ----
        f32x4 acc = (f32x4){0.f, 0.f, 0.f, 0.f};
#pragma unroll
        for (int ks = 0; ks < 16; ++ks) {
            const int kabs = kh * 16 + ks;
            const int slot = (kabs * 4 + g) ^ (c & 7);
            bf16x8 af = *(const bf16x8*)((const char*)(&Abuf[s & 1][0]) + c * 2048 + (slot << 4));
            bf16x8 bfrag;
            if constexpr (PREPPED) {
                bfrag = *(const bf16x8*)(Bb + ks * 32 + g * 8);
            } else {
                const float* fp = Bf + ks * 32 + g * 8;
                f32x4 b0 = *(const f32x4*)(fp);
                f32x4 b1 = *(const f32x4*)(fp + 4);
                bfrag[0] = f2bf_s(b0[0]); bfrag[1] = f2bf_s(b0[1]);
                bfrag[2] = f2bf_s(b0[2]); bfrag[3] = f2bf_s(b0[3]);
                bfrag[4] = f2bf_s(b1[0]); bfrag[5] = f2bf_s(b1[1]);
                bfrag[6] = f2bf_s(b1[2]); bfrag[7] = f2bf_s(b1[3]);
            }
            acc = __builtin_amdgcn_mfma_f32_16x16x32_bf16(af, bfrag, acc, 0, 0, 0);
        }

        // ---- per-phase epilogue ----
        if (kh == 1) *(f32x4*)(&eps[tt][lane][0]) = acc;   // publish K-half-1 partials
        phase_barrier();                                    // also closes Abuf[s&1] reads
        if (kh == 0) {
            f32x4 oth = *(const f32x4*)(&eps[tt][lane][0]);
#pragma unroll
            for (int reg = 0; reg < 4; ++reg) {
                const float logit = acc[reg] + oth[reg] - thr_t;
                const float p = 1.0f / (1.0f + __expf(-logit));
                float o0 = w10 + p * dd0;
                float o1 = w11 + p * dd1;
#pragma unroll
                for (int m = 1; m < 16; m <<= 1) {   // sum 16 trees (c bits)
                    o0 += __shfl_xor(o0, m, 64);
                    o1 += __shfl_xor(o1, m, 64);
                }
                if (c == 0) {
                    part[tt][g * 4 + reg][0] = o0;
                    part[tt][g * 4 + reg][1] = o1;
                }
            }
        }
        phase_barrier();
        if (tid < 32) {
            const int row = tid >> 1, o = tid & 1;
            out[(blockRow + s * SROWS + row) * 2 + o] =
                part[0][row][o] + part[1][row][o] + part[2][row][o] + part[3][row][o];
        }
    }
}

extern "C" void kernel_launch(void* const* d_in, const int* in_sizes, int n_in,
                              void* d_out, int out_size, void* d_ws, size_t ws_size,
                              hipStream_t stream) {
    const float* x   = (const float*)d_in[0];
    const float* fs  = (const float*)d_in[1];
    const float* thr = (const float*)d_in[2];
    const float* lw  = (const float*)d_in[3];
    float* out = (float*)d_out;
    (void)in_sizes; (void)n_in; (void)out_size;

    const size_t FB_BYTES = (size_t)NT * ND * sizeof(__hip_bfloat16);  // 128 KB
    if (ws_size >= FB_BYTES) {
        __hip_bfloat16* Fb = (__hip_bfloat16*)d_ws;
        prep_kernel<<<256, 256, 0, stream>>>(fs, Fb);
        node_main<true><<<NBLK, TPB, 0, stream>>>(x, (const void*)Fb, thr, lw, out);
    } else {
        node_main<false><<<NBLK, TPB, 0, stream>>>(x, (const void*)fs, thr, lw, out);
    }
}

// Round 10
// 50.691 us; speedup vs baseline: 2.0757x; 2.0757x over previous
//
#include <hip/hip_runtime.h>
#include <hip/hip_bf16.h>

// Problem constants
#define NB    65536      // batch rows
#define ND    1024       // feature dim (K)
#define NT    64         // trees (N)
#define BK    64         // K-chunk in floats
#define NCH   (ND / BK)  // 16 chunks
#define ROWS  64         // rows per block (4 waves; wave w owns trees [16w,16w+16))

typedef __attribute__((ext_vector_type(8))) short bf16x8;
typedef __attribute__((ext_vector_type(4))) short bf16x4;
typedef __attribute__((ext_vector_type(4))) float f32x4;

__device__ __forceinline__ short f2bf_s(float f) {
    __hip_bfloat16 h = __float2bfloat16(f);
    return __builtin_bit_cast(short, h);
}

// lgkm-only barrier (no vmcnt drain) — proven correct R6.
__device__ __forceinline__ void phase_barrier() {
    asm volatile("s_waitcnt lgkmcnt(0)\n\ts_barrier" ::: "memory");
}

// ---- prep: feature_selectors [64][1024] f32 -> bf16 in d_ws ----
__global__ __launch_bounds__(256) void prep_kernel(const float* __restrict__ F,
                                                   __hip_bfloat16* __restrict__ Fb) {
    int idx = blockIdx.x * 256 + threadIdx.x;  // 256 blocks -> 65536 elements
    Fb[idx] = __float2bfloat16(F[idx]);
}

// R6 structure + register-double-buffered B. Key invariant: every load is
// consumed only when it is OLD in the vmcnt FIFO (>= 1 full phase), so counted
// vmcnt waits never drain the in-flight A-chunk HBM loads.
template <bool PREPPED>
__global__ __launch_bounds__(256, 4) void node_main(const float* __restrict__ x,
                                                    const void* __restrict__ Fv,
                                                    const float* __restrict__ thr,
                                                    const float* __restrict__ lw,
                                                    float* __restrict__ out) {
    __shared__ __align__(16) __hip_bfloat16 Abuf[2][ROWS * BK];   // 2 x 8 KB

    const int tid  = threadIdx.x;
    const int w    = tid >> 6;
    const int lane = tid & 63;
    const int c    = lane & 15;     // MFMA 16-index: batch row (A) / tree col (B)
    const int g    = lane >> 4;     // k-group
    const long blockRow = (long)blockIdx.x * ROWS;
    const float* xbase = x + blockRow * ND;

    // staging: pass i covers rows i*16 + srow; 16 lanes x 16B = 256B contiguous per row
    const int srow = tid >> 4;      // 0..15
    const int scol = tid & 15;      // f32x4 granule within row-chunk

    // per-lane tree constants (one tree per lane within the wave's 16-tree tile)
    const int   t     = w * 16 + c;
    const float thr_t = thr[t];
    const float w00 = lw[t * 4 + 0], w01 = lw[t * 4 + 1];
    const float w10 = lw[t * 4 + 2], w11 = lw[t * 4 + 3];
    const __hip_bfloat16* Fbrow = (const __hip_bfloat16*)Fv + (long)t * ND;
    const float*          Ffrow = (const float*)Fv          + (long)t * ND;

    f32x4 acc[4];
#pragma unroll
    for (int rt = 0; rt < 4; ++rt) acc[rt] = (f32x4){0.f, 0.f, 0.f, 0.f};

    f32x4  rA0[4], rA1[4];   // A chunk staging regs (2 phases deep)
    bf16x8 rB0[2], rB1[2];   // B fragment regs (1 phase deep)

    auto load_chunk = [&](int ch, f32x4* rA) {
#pragma unroll
        for (int i = 0; i < 4; ++i) {
            const int r = i * 16 + srow;
            rA[i] = *(const f32x4*)(xbase + (long)r * ND + ch * BK + scol * 4);
        }
    };
    auto loadB = [&](int ch, bf16x8* rB) {
        if constexpr (PREPPED) {
            rB[0] = *(const bf16x8*)(Fbrow + ch * BK + g * 8);
            rB[1] = *(const bf16x8*)(Fbrow + ch * BK + 32 + g * 8);
        } else {
#pragma unroll
            for (int kk = 0; kk < 2; ++kk) {
                const float* fp = Ffrow + ch * BK + kk * 32 + g * 8;
                f32x4 b0 = *(const f32x4*)(fp);
                f32x4 b1 = *(const f32x4*)(fp + 4);
                bf16x8 bf;
                bf[0] = f2bf_s(b0[0]); bf[1] = f2bf_s(b0[1]);
                bf[2] = f2bf_s(b0[2]); bf[3] = f2bf_s(b0[3]);
                bf[4] = f2bf_s(b1[0]); bf[5] = f2bf_s(b1[1]);
                bf[6] = f2bf_s(b1[2]); bf[7] = f2bf_s(b1[3]);
                rB[kk] = bf;
            }
        }
    };
    auto stage_write = [&](int buf, const f32x4* rA) {
#pragma unroll
        for (int i = 0; i < 4; ++i) {
            const int r = i * 16 + srow;
            f32x4 a = rA[i];
            bf16x4 v;
            v[0] = f2bf_s(a[0]); v[1] = f2bf_s(a[1]);
            v[2] = f2bf_s(a[2]); v[3] = f2bf_s(a[3]);
            const int s = (scol >> 1) ^ (r & 7);      // T2 XOR swizzle, 16B slots
            char* p = (char*)(&Abuf[buf][0]) + r * 128 + (s << 4) + ((scol & 1) << 3);
            *(bf16x4*)p = v;
        }
    };
    auto compute = [&](int buf, const bf16x8* rB) {
#pragma unroll
        for (int kk = 0; kk < 2; ++kk) {
#pragma unroll
            for (int rt = 0; rt < 4; ++rt) {
                const int r    = rt * 16 + c;
                const int slot = (kk * 4 + g) ^ (r & 7);
                bf16x8 afrag = *(const bf16x8*)(&Abuf[buf][r * BK + slot * 8]);
                acc[rt] = __builtin_amdgcn_mfma_f32_16x16x32_bf16(afrag, rB[kk], acc[rt], 0, 0, 0);
            }
        }
    };

    // prologue: A chunks 0,1 and B fragments 0,1 in flight; stage 0
    load_chunk(0, rA0);
    load_chunk(1, rA1);
    loadB(0, rB0);
    loadB(1, rB1);
    stage_write(0, rA0);
    phase_barrier();

#pragma unroll
    for (int ch2 = 0; ch2 < NCH; ch2 += 2) {
        // ---- even phase: buf0 holds ch2, rB0 holds B(ch2) ----
        if (ch2 + 2 < NCH) load_chunk(ch2 + 2, rA0);
        compute(0, rB0);                       // waits only on phase-old loads
        if (ch2 + 2 < NCH) loadB(ch2 + 2, rB0);  // refill AFTER use; lands next phase
        stage_write(1, rA1);                   // rA1 loaded a full phase ago
        phase_barrier();
        // ---- odd phase: buf1 holds ch2+1, rB1 holds B(ch2+1) ----
        if (ch2 + 3 < NCH) load_chunk(ch2 + 3, rA1);
        compute(1, rB1);
        if (ch2 + 3 < NCH) loadB(ch2 + 3, rB1);
        if (ch2 + 2 < NCH) stage_write(0, rA0);
        phase_barrier();
    }

    // ---- epilogue: sigmoid + leaf combine + tree reduction (proven R6) ----
    float* partials = (float*)(&Abuf[0][0]);   // aliased; safe after last phase_barrier
#pragma unroll
    for (int rt = 0; rt < 4; ++rt) {
#pragma unroll
        for (int reg = 0; reg < 4; ++reg) {
            const float logit = acc[rt][reg] - thr_t;
            const float p = 1.0f / (1.0f + __expf(-logit));
            float o0 = w10 + p * (w00 - w10);
            float o1 = w11 + p * (w01 - w11);
#pragma unroll
            for (int m = 1; m < 16; m <<= 1) {   // butterfly over 16 trees (c bits)
                o0 += __shfl_xor(o0, m, 64);
                o1 += __shfl_xor(o1, m, 64);
            }
            if (c == 0) {
                const int row = rt * 16 + g * 4 + reg;
                partials[(w * ROWS + row) * 2 + 0] = o0;
                partials[(w * ROWS + row) * 2 + 1] = o1;
            }
        }
    }
    __syncthreads();
    if (tid < 128) {
        const int row = tid >> 1, o = tid & 1;
        const float s = partials[(0 * ROWS + row) * 2 + o] + partials[(1 * ROWS + row) * 2 + o] +
                        partials[(2 * ROWS + row) * 2 + o] + partials[(3 * ROWS + row) * 2 + o];
        out[(blockRow + row) * 2 + o] = s;
    }
}

extern "C" void kernel_launch(void* const* d_in, const int* in_sizes, int n_in,
                              void* d_out, int out_size, void* d_ws, size_t ws_size,
                              hipStream_t stream) {
    const float* x   = (const float*)d_in[0];
    const float* fs  = (const float*)d_in[1];
    const float* thr = (const float*)d_in[2];
    const float* lw  = (const float*)d_in[3];
    float* out = (float*)d_out;
    (void)in_sizes; (void)n_in; (void)out_size;

    const size_t FB_BYTES = (size_t)NT * ND * sizeof(__hip_bfloat16);  // 128 KB
    if (ws_size >= FB_BYTES) {
        __hip_bfloat16* Fb = (__hip_bfloat16*)d_ws;
        prep_kernel<<<256, 256, 0, stream>>>(fs, Fb);
        node_main<true><<<NB / ROWS, 256, 0, stream>>>(x, (const void*)Fb, thr, lw, out);
    } else {
        node_main<false><<<NB / ROWS, 256, 0, stream>>>(x, (const void*)fs, thr, lw, out);
    }
}

// Round 11
// 50.059 us; speedup vs baseline: 2.1019x; 1.0126x over previous
//
#include <hip/hip_runtime.h>
#include <hip/hip_bf16.h>

// Problem constants
#define NB    65536      // batch rows
#define ND    1024       // feature dim (K)
#define NT    64         // trees (N)
#define BK    64         // K-chunk in floats
#define NCH   (ND / BK)  // 16 chunks
#define ROWS  64         // rows per block (4 waves; wave w owns trees [16w,16w+16))

typedef __attribute__((ext_vector_type(8))) short bf16x8;
typedef __attribute__((ext_vector_type(4))) short bf16x4;
typedef __attribute__((ext_vector_type(4))) float f32x4;

__device__ __forceinline__ short f2bf_s(float f) {
    __hip_bfloat16 h = __float2bfloat16(f);
    return __builtin_bit_cast(short, h);
}

// lgkm-only barrier (no vmcnt drain) — proven correct R6.
__device__ __forceinline__ void phase_barrier() {
    asm volatile("s_waitcnt lgkmcnt(0)\n\ts_barrier" ::: "memory");
}

// ---- prep: feature_selectors [64][1024] f32 -> bf16 in d_ws ----
__global__ __launch_bounds__(256) void prep_kernel(const float* __restrict__ F,
                                                   __hip_bfloat16* __restrict__ Fb) {
    int idx = blockIdx.x * 256 + threadIdx.x;  // 256 blocks -> 65536 elements
    Fb[idx] = __float2bfloat16(F[idx]);
}

// R10 structure + per-block K-chunk rotation: block b processes chunks in order
// (b, b+1, ... mod 16). Within a phase, a block's 64 segments share addr bits
// [8:11] (4KB row stride); rotation makes concurrent blocks differ in those
// bits -> uniform HBM channel load instead of systemic hotspots.
template <bool PREPPED>
__global__ __launch_bounds__(256, 4) void node_main(const float* __restrict__ x,
                                                    const void* __restrict__ Fv,
                                                    const float* __restrict__ thr,
                                                    const float* __restrict__ lw,
                                                    float* __restrict__ out) {
    __shared__ __align__(16) __hip_bfloat16 Abuf[2][ROWS * BK];   // 2 x 8 KB

    const int tid  = threadIdx.x;
    const int w    = tid >> 6;
    const int lane = tid & 63;
    const int c    = lane & 15;     // MFMA 16-index: batch row (A) / tree col (B)
    const int g    = lane >> 4;     // k-group
    const int rot  = blockIdx.x & (NCH - 1);   // per-block K-schedule rotation
    const long blockRow = (long)blockIdx.x * ROWS;
    const float* xbase = x + blockRow * ND;

    // staging: pass i covers rows i*16 + srow; 16 lanes x 16B = 256B contiguous per row
    const int srow = tid >> 4;      // 0..15
    const int scol = tid & 15;      // f32x4 granule within row-chunk

    // per-lane tree constants (one tree per lane within the wave's 16-tree tile)
    const int   t     = w * 16 + c;
    const float thr_t = thr[t];
    const float w00 = lw[t * 4 + 0], w01 = lw[t * 4 + 1];
    const float w10 = lw[t * 4 + 2], w11 = lw[t * 4 + 3];
    const __hip_bfloat16* Fbrow = (const __hip_bfloat16*)Fv + (long)t * ND;
    const float*          Ffrow = (const float*)Fv          + (long)t * ND;

    f32x4 acc[4];
#pragma unroll
    for (int rt = 0; rt < 4; ++rt) acc[rt] = (f32x4){0.f, 0.f, 0.f, 0.f};

    f32x4  rA0[4], rA1[4];   // A chunk staging regs (2 phases deep)
    bf16x8 rB0[2], rB1[2];   // B fragment regs (1 phase deep)

    auto chmap = [&](int ch) { return (ch + rot) & (NCH - 1); };

    auto load_chunk = [&](int ch, f32x4* rA) {
        const int cm = chmap(ch);
#pragma unroll
        for (int i = 0; i < 4; ++i) {
            const int r = i * 16 + srow;
            rA[i] = *(const f32x4*)(xbase + (long)r * ND + cm * BK + scol * 4);
        }
    };
    auto loadB = [&](int ch, bf16x8* rB) {
        const int cm = chmap(ch);
        if constexpr (PREPPED) {
            rB[0] = *(const bf16x8*)(Fbrow + cm * BK + g * 8);
            rB[1] = *(const bf16x8*)(Fbrow + cm * BK + 32 + g * 8);
        } else {
#pragma unroll
            for (int kk = 0; kk < 2; ++kk) {
                const float* fp = Ffrow + cm * BK + kk * 32 + g * 8;
                f32x4 b0 = *(const f32x4*)(fp);
                f32x4 b1 = *(const f32x4*)(fp + 4);
                bf16x8 bf;
                bf[0] = f2bf_s(b0[0]); bf[1] = f2bf_s(b0[1]);
                bf[2] = f2bf_s(b0[2]); bf[3] = f2bf_s(b0[3]);
                bf[4] = f2bf_s(b1[0]); bf[5] = f2bf_s(b1[1]);
                bf[6] = f2bf_s(b1[2]); bf[7] = f2bf_s(b1[3]);
                rB[kk] = bf;
            }
        }
    };
    auto stage_write = [&](int buf, const f32x4* rA) {
#pragma unroll
        for (int i = 0; i < 4; ++i) {
            const int r = i * 16 + srow;
            f32x4 a = rA[i];
            bf16x4 v;
            v[0] = f2bf_s(a[0]); v[1] = f2bf_s(a[1]);
            v[2] = f2bf_s(a[2]); v[3] = f2bf_s(a[3]);
            const int s = (scol >> 1) ^ (r & 7);      // T2 XOR swizzle, 16B slots
            char* p = (char*)(&Abuf[buf][0]) + r * 128 + (s << 4) + ((scol & 1) << 3);
            *(bf16x4*)p = v;
        }
    };
    auto compute = [&](int buf, const bf16x8* rB) {
#pragma unroll
        for (int kk = 0; kk < 2; ++kk) {
#pragma unroll
            for (int rt = 0; rt < 4; ++rt) {
                const int r    = rt * 16 + c;
                const int slot = (kk * 4 + g) ^ (r & 7);
                bf16x8 afrag = *(const bf16x8*)(&Abuf[buf][r * BK + slot * 8]);
                acc[rt] = __builtin_amdgcn_mfma_f32_16x16x32_bf16(afrag, rB[kk], acc[rt], 0, 0, 0);
            }
        }
    };

    // prologue: A chunks 0,1 and B fragments 0,1 in flight; stage 0
    load_chunk(0, rA0);
    load_chunk(1, rA1);
    loadB(0, rB0);
    loadB(1, rB1);
    stage_write(0, rA0);
    phase_barrier();

#pragma unroll
    for (int ch2 = 0; ch2 < NCH; ch2 += 2) {
        // ---- even phase: buf0 holds ch2, rB0 holds B(ch2) ----
        if (ch2 + 2 < NCH) load_chunk(ch2 + 2, rA0);
        compute(0, rB0);                         // waits only on phase-old loads
        if (ch2 + 2 < NCH) loadB(ch2 + 2, rB0);  // refill AFTER use; lands next phase
        stage_write(1, rA1);                     // rA1 loaded a full phase ago
        phase_barrier();
        // ---- odd phase: buf1 holds ch2+1, rB1 holds B(ch2+1) ----
        if (ch2 + 3 < NCH) load_chunk(ch2 + 3, rA1);
        compute(1, rB1);
        if (ch2 + 3 < NCH) loadB(ch2 + 3, rB1);
        if (ch2 + 2 < NCH) stage_write(0, rA0);
        phase_barrier();
    }

    // ---- epilogue: sigmoid + leaf combine + tree reduction (proven R6) ----
    float* partials = (float*)(&Abuf[0][0]);   // aliased; safe after last phase_barrier
#pragma unroll
    for (int rt = 0; rt < 4; ++rt) {
#pragma unroll
        for (int reg = 0; reg < 4; ++reg) {
            const float logit = acc[rt][reg] - thr_t;
            const float p = 1.0f / (1.0f + __expf(-logit));
            float o0 = w10 + p * (w00 - w10);
            float o1 = w11 + p * (w01 - w11);
#pragma unroll
            for (int m = 1; m < 16; m <<= 1) {   // butterfly over 16 trees (c bits)
                o0 += __shfl_xor(o0, m, 64);
                o1 += __shfl_xor(o1, m, 64);
            }
            if (c == 0) {
                const int row = rt * 16 + g * 4 + reg;
                partials[(w * ROWS + row) * 2 + 0] = o0;
                partials[(w * ROWS + row) * 2 + 1] = o1;
            }
        }
    }
    __syncthreads();
    if (tid < 128) {
        const int row = tid >> 1, o = tid & 1;
        const float s = partials[(0 * ROWS + row) * 2 + o] + partials[(1 * ROWS + row) * 2 + o] +
                        partials[(2 * ROWS + row) * 2 + o] + partials[(3 * ROWS + row) * 2 + o];
        out[(blockRow + row) * 2 + o] = s;
    }
}

extern "C" void kernel_launch(void* const* d_in, const int* in_sizes, int n_in,
                              void* d_out, int out_size, void* d_ws, size_t ws_size,
                              hipStream_t stream) {
    const float* x   = (const float*)d_in[0];
    const float* fs  = (const float*)d_in[1];
    const float* thr = (const float*)d_in[2];
    const float* lw  = (const float*)d_in[3];
    float* out = (float*)d_out;
    (void)in_sizes; (void)n_in; (void)out_size;

    const size_t FB_BYTES = (size_t)NT * ND * sizeof(__hip_bfloat16);  // 128 KB
    if (ws_size >= FB_BYTES) {
        __hip_bfloat16* Fb = (__hip_bfloat16*)d_ws;
        prep_kernel<<<256, 256, 0, stream>>>(fs, Fb);
        node_main<true><<<NB / ROWS, 256, 0, stream>>>(x, (const void*)Fb, thr, lw, out);
    } else {
        node_main<false><<<NB / ROWS, 256, 0, stream>>>(x, (const void*)fs, thr, lw, out);
    }
}

// Round 12
// 49.288 us; speedup vs baseline: 2.1348x; 1.0156x over previous
//
#include <hip/hip_runtime.h>
#include <hip/hip_bf16.h>

// Problem constants
#define NB    65536      // batch rows
#define ND    1024       // feature dim (K)
#define NT    64         // trees (N)
#define BK    64         // K-chunk in floats
#define NCH   (ND / BK)  // 16 chunks
#define ROWS  64         // rows per block (4 waves; wave w owns trees [16w,16w+16))

typedef __attribute__((ext_vector_type(8))) short bf16x8;
typedef __attribute__((ext_vector_type(4))) short bf16x4;
typedef __attribute__((ext_vector_type(4))) float f32x4;

__device__ __forceinline__ short f2bf_s(float f) {
    __hip_bfloat16 h = __float2bfloat16(f);
    return __builtin_bit_cast(short, h);
}

// lgkm-only barrier (no vmcnt drain) — proven correct R6.
__device__ __forceinline__ void phase_barrier() {
    asm volatile("s_waitcnt lgkmcnt(0)\n\ts_barrier" ::: "memory");
}

// Single kernel (no prep): B loaded as f32 from L2 with inline cvt. R10/R11
// structure otherwise verbatim: LDS-staged A (XOR-swizzled, double-buffered),
// 2-phase-deep A register staging, 1-phase-deep B register staging so counted
// vmcnt waits never drain in-flight A HBM loads, per-block K-chunk rotation.
__global__ __launch_bounds__(256, 4) void node_main(const float* __restrict__ x,
                                                    const float* __restrict__ F,
                                                    const float* __restrict__ thr,
                                                    const float* __restrict__ lw,
                                                    float* __restrict__ out) {
    __shared__ __align__(16) __hip_bfloat16 Abuf[2][ROWS * BK];   // 2 x 8 KB

    const int tid  = threadIdx.x;
    const int w    = tid >> 6;
    const int lane = tid & 63;
    const int c    = lane & 15;     // MFMA 16-index: batch row (A) / tree col (B)
    const int g    = lane >> 4;     // k-group
    const int rot  = blockIdx.x & (NCH - 1);   // per-block K-schedule rotation
    const long blockRow = (long)blockIdx.x * ROWS;
    const float* xbase = x + blockRow * ND;

    // staging: pass i covers rows i*16 + srow; 16 lanes x 16B = 256B contiguous per row
    const int srow = tid >> 4;      // 0..15
    const int scol = tid & 15;      // f32x4 granule within row-chunk

    // per-lane tree constants (one tree per lane within the wave's 16-tree tile)
    const int   t     = w * 16 + c;
    const float thr_t = thr[t];
    const float w00 = lw[t * 4 + 0], w01 = lw[t * 4 + 1];
    const float w10 = lw[t * 4 + 2], w11 = lw[t * 4 + 3];
    const float* Ffrow = F + (long)t * ND;   // f32 B row, L2-resident

    f32x4 acc[4];
#pragma unroll
    for (int rt = 0; rt < 4; ++rt) acc[rt] = (f32x4){0.f, 0.f, 0.f, 0.f};

    f32x4  rA0[4], rA1[4];   // A chunk staging regs (2 phases deep)
    bf16x8 rB0[2], rB1[2];   // B fragment regs (1 phase deep)

    auto chmap = [&](int ch) { return (ch + rot) & (NCH - 1); };

    auto load_chunk = [&](int ch, f32x4* rA) {
        const int cm = chmap(ch);
#pragma unroll
        for (int i = 0; i < 4; ++i) {
            const int r = i * 16 + srow;
            rA[i] = *(const f32x4*)(xbase + (long)r * ND + cm * BK + scol * 4);
        }
    };
    auto loadB = [&](int ch, bf16x8* rB) {
        const int cm = chmap(ch);
#pragma unroll
        for (int kk = 0; kk < 2; ++kk) {
            const float* fp = Ffrow + cm * BK + kk * 32 + g * 8;
            f32x4 b0 = *(const f32x4*)(fp);
            f32x4 b1 = *(const f32x4*)(fp + 4);
            bf16x8 bf;
            bf[0] = f2bf_s(b0[0]); bf[1] = f2bf_s(b0[1]);
            bf[2] = f2bf_s(b0[2]); bf[3] = f2bf_s(b0[3]);
            bf[4] = f2bf_s(b1[0]); bf[5] = f2bf_s(b1[1]);
            bf[6] = f2bf_s(b1[2]); bf[7] = f2bf_s(b1[3]);
            rB[kk] = bf;
        }
    };
    auto stage_write = [&](int buf, const f32x4* rA) {
#pragma unroll
        for (int i = 0; i < 4; ++i) {
            const int r = i * 16 + srow;
            f32x4 a = rA[i];
            bf16x4 v;
            v[0] = f2bf_s(a[0]); v[1] = f2bf_s(a[1]);
            v[2] = f2bf_s(a[2]); v[3] = f2bf_s(a[3]);
            const int s = (scol >> 1) ^ (r & 7);      // T2 XOR swizzle, 16B slots
            char* p = (char*)(&Abuf[buf][0]) + r * 128 + (s << 4) + ((scol & 1) << 3);
            *(bf16x4*)p = v;
        }
    };
    auto compute = [&](int buf, const bf16x8* rB) {
#pragma unroll
        for (int kk = 0; kk < 2; ++kk) {
#pragma unroll
            for (int rt = 0; rt < 4; ++rt) {
                const int r    = rt * 16 + c;
                const int slot = (kk * 4 + g) ^ (r & 7);
                bf16x8 afrag = *(const bf16x8*)(&Abuf[buf][r * BK + slot * 8]);
                acc[rt] = __builtin_amdgcn_mfma_f32_16x16x32_bf16(afrag, rB[kk], acc[rt], 0, 0, 0);
            }
        }
    };

    // prologue: A chunks 0,1 and B fragments 0,1 in flight; stage 0
    load_chunk(0, rA0);
    load_chunk(1, rA1);
    loadB(0, rB0);
    loadB(1, rB1);
    stage_write(0, rA0);
    phase_barrier();

#pragma unroll
    for (int ch2 = 0; ch2 < NCH; ch2 += 2) {
        // ---- even phase: buf0 holds ch2, rB0 holds B(ch2) ----
        if (ch2 + 2 < NCH) load_chunk(ch2 + 2, rA0);
        compute(0, rB0);                         // waits only on phase-old loads
        if (ch2 + 2 < NCH) loadB(ch2 + 2, rB0);  // refill AFTER use; lands next phase
        stage_write(1, rA1);                     // rA1 loaded a full phase ago
        phase_barrier();
        // ---- odd phase: buf1 holds ch2+1, rB1 holds B(ch2+1) ----
        if (ch2 + 3 < NCH) load_chunk(ch2 + 3, rA1);
        compute(1, rB1);
        if (ch2 + 3 < NCH) loadB(ch2 + 3, rB1);
        if (ch2 + 2 < NCH) stage_write(0, rA0);
        phase_barrier();
    }

    // ---- epilogue: sigmoid + leaf combine + tree reduction (proven R6) ----
    float* partials = (float*)(&Abuf[0][0]);   // aliased; safe after last phase_barrier
#pragma unroll
    for (int rt = 0; rt < 4; ++rt) {
#pragma unroll
        for (int reg = 0; reg < 4; ++reg) {
            const float logit = acc[rt][reg] - thr_t;
            const float p = 1.0f / (1.0f + __expf(-logit));
            float o0 = w10 + p * (w00 - w10);
            float o1 = w11 + p * (w01 - w11);
#pragma unroll
            for (int m = 1; m < 16; m <<= 1) {   // butterfly over 16 trees (c bits)
                o0 += __shfl_xor(o0, m, 64);
                o1 += __shfl_xor(o1, m, 64);
            }
            if (c == 0) {
                const int row = rt * 16 + g * 4 + reg;
                partials[(w * ROWS + row) * 2 + 0] = o0;
                partials[(w * ROWS + row) * 2 + 1] = o1;
            }
        }
    }
    __syncthreads();
    if (tid < 128) {
        const int row = tid >> 1, o = tid & 1;
        const float s = partials[(0 * ROWS + row) * 2 + o] + partials[(1 * ROWS + row) * 2 + o] +
                        partials[(2 * ROWS + row) * 2 + o] + partials[(3 * ROWS + row) * 2 + o];
        out[(blockRow + row) * 2 + o] = s;
    }
}

extern "C" void kernel_launch(void* const* d_in, const int* in_sizes, int n_in,
                              void* d_out, int out_size, void* d_ws, size_t ws_size,
                              hipStream_t stream) {
    const float* x   = (const float*)d_in[0];
    const float* fs  = (const float*)d_in[1];
    const float* thr = (const float*)d_in[2];
    const float* lw  = (const float*)d_in[3];
    float* out = (float*)d_out;
    (void)in_sizes; (void)n_in; (void)out_size; (void)d_ws; (void)ws_size;

    node_main<<<NB / ROWS, 256, 0, stream>>>(x, fs, thr, lw, out);
}